// Round 2
// baseline (611.668 us; speedup 1.0000x reference)
//
#include <hip/hip_runtime.h>
#include <hip/hip_bf16.h>

#define NCOLS 32768
#define NZ 64
#define NT 40
#define DTF 30.0f
#define GAMMAC 0.55f

typedef _Float16 f16;

// swap lanes (0,1) and (2,3) within each quad: u<->v, t<->s
__device__ __forceinline__ float dpp_swap1(float x) {
    return __int_as_float(__builtin_amdgcn_mov_dpp(__float_as_int(x), 0xB1, 0xF, 0xF, true));
}
__device__ __forceinline__ unsigned int packh2(float a, float b) {
    union { f16 h[2]; unsigned int u; } v;
    v.h[0] = (f16)a; v.h[1] = (f16)b;
    return v.u;
}
__device__ __forceinline__ float lo16f(unsigned int x) {
    union { unsigned int u; f16 h[2]; } v; v.u = x;
    return (float)v.h[0];
}
__device__ __forceinline__ float hi16f(unsigned int x) {
    union { unsigned int u; f16 h[2]; } v; v.u = x;
    return (float)v.h[1];
}

__global__ __launch_bounds__(256, 2) void scm_kernel(
    const float* __restrict__ u0, const float* __restrict__ v0,
    const float* __restrict__ t0, const float* __restrict__ s0,
    const float* __restrict__ hz, const float* __restrict__ akv,
    const float* __restrict__ akt, const float* __restrict__ tfo,
    const float* __restrict__ sfo, const float* __restrict__ uss,
    const float* __restrict__ vss, const float* __restrict__ usb,
    const float* __restrict__ vsb, const float* __restrict__ fcor,
    float* __restrict__ out)
{
    const int tid = blockIdx.x * 256 + threadIdx.x;
    const int field = tid & 3;          // 0=u 1=v 2=t 3=s
    const int col = tid >> 2;

    const float* ak  = (field < 2) ? akv : akt;
    const float* st0 = (field == 0) ? u0 : (field == 1) ? v0 : (field == 2) ? t0 : s0;

    // per-column Coriolis scalars (u,v only)
    float alpha = 1.0f, beta = 0.0f;
    {
        float fc   = fcor[col];
        float dtfc = DTF * fc;
        float cff  = dtfc * dtfc;
        float cff1 = 1.0f / (1.0f + GAMMAC * GAMMAC * cff);
        float coefc = 1.0f - GAMMAC * (1.0f - GAMMAC) * cff;
        if (field == 0)      { alpha = cff1 * coefc; beta =  cff1 * dtfc; }
        else if (field == 1) { alpha = cff1 * coefc; beta = -cff1 * dtfc; }
    }

    float bnd0 = 0.f, bnd63 = 0.f;
    if (field == 0)      { bnd0 = -DTF * usb[col]; bnd63 = DTF * uss[col]; }
    else if (field == 1) { bnd0 = -DTF * vsb[col]; bnd63 = DTF * vss[col]; }

    // ---- load hz ----
    float hzv[NZ];
    {
        const float4* hp = (const float4*)(hz + (size_t)col * NZ);
        #pragma unroll
        for (int k4 = 0; k4 < NZ / 4; ++k4) {
            float4 h = hp[k4];
            hzv[4*k4+0] = h.x; hzv[4*k4+1] = h.y;
            hzv[4*k4+2] = h.z; hzv[4*k4+3] = h.w;
        }
    }

    const float* akc = ak + (size_t)col * (NZ + 1);
    const float* fr  = ((field == 2) ? tfo : sfo) + (size_t)col * NZ;

    // ---- precompute folded Thomas coefficients, fp16-packed ----
    // a[k] = -2dt*ak[k]/(hz[k-1]+hz[k]) (a[0]=0); c[k] = a[k+1] (c[63]=0)
    // b[k] = hz[k]-a[k]-c[k]; g=1/(b-a*cp_prev); cp=c*g
    // fwd: dp[k] = hg[k]*(alpha*own+beta*oth) + fg[k] - e[k]*dp[k-1]
    unsigned int hgfg[NZ], ecp[NZ];
    {
        float cpprev = 0.f;
        float aik = 0.f;               // a[0] = 0
        #pragma unroll
        for (int k = 0; k < NZ; ++k) {
            float aik1 = 0.f;
            if (k < NZ - 1)
                aik1 = (-2.0f * DTF) * akc[k + 1] / (hzv[k] + hzv[k + 1]);
            float bk    = hzv[k] - aik - aik1;
            float denom = bk - aik * cpprev;
            float g     = 1.0f / denom;
            float cpk   = aik1 * g;
            float fgk;
            if (field >= 2) fgk = (DTF * fr[k]) * g;
            else            fgk = (k == 0 ? bnd0 : (k == NZ - 1 ? bnd63 : 0.0f)) * g;
            hgfg[k] = packh2(hzv[k] * g, fgk);
            ecp[k]  = packh2(-aik * g, -cpk);
            cpprev = cpk;
            aik = aik1;
        }
    }

    // ---- load state ----
    float tau[NZ];
    {
        const float4* sp = (const float4*)(st0 + (size_t)col * NZ);
        #pragma unroll
        for (int k4 = 0; k4 < NZ / 4; ++k4) {
            float4 s = sp[k4];
            tau[4*k4+0] = s.x; tau[4*k4+1] = s.y;
            tau[4*k4+2] = s.z; tau[4*k4+3] = s.w;
        }
    }

    // deviation shift for t,s: the solve conserves constants exactly
    // (row sums of M equal hz), so evolve tau = state - mean and re-add at
    // the end. Keeps state O(1) so fp16 coefficient rounding cannot excite
    // the conserved mode (which would accumulate linearly over 40 steps).
    float meanadd = 0.0f;
    if (field >= 2) {
        float ssum = 0.f;
        #pragma unroll
        for (int k = 0; k < NZ; ++k) ssum += tau[k];
        meanadd = ssum * (1.0f / NZ);
        #pragma unroll
        for (int k = 0; k < NZ; ++k) tau[k] -= meanadd;
    }

    // ---- 40 time steps, fully in registers ----
    for (int n = 0; n < NT; ++n) {
        float dpprev = 0.f;
        #pragma unroll
        for (int k = 0; k < NZ; ++k) {
            float own = tau[k];
            float oth = dpp_swap1(own);                // partner field's value
            float m   = fmaf(beta, oth, alpha * own);  // t,s: beta=0,alpha=1
            unsigned int hf = hgfg[k];
            float dp  = fmaf(lo16f(hf), m, hi16f(hf)); // hg*m + fg
            dp = fmaf(lo16f(ecp[k]), dpprev, dp);      // - e*dp_prev
            tau[k] = dp;
            dpprev = dp;
        }
        float xn = 0.f;
        #pragma unroll
        for (int k = NZ - 1; k >= 0; --k) {
            float x = fmaf(hi16f(ecp[k]), xn, tau[k]); // dp - cp*x_next
            tau[k] = x;
            xn = x;
        }
    }

    // ---- store f32 output: out[field][col][k] ----
    float* op = out + ((size_t)field * NCOLS + col) * NZ;
    #pragma unroll
    for (int k4 = 0; k4 < NZ / 4; ++k4) {
        float4 w;
        w.x = tau[4*k4+0] + meanadd;
        w.y = tau[4*k4+1] + meanadd;
        w.z = tau[4*k4+2] + meanadd;
        w.w = tau[4*k4+3] + meanadd;
        ((float4*)op)[k4] = w;
    }
}

extern "C" void kernel_launch(void* const* d_in, const int* in_sizes, int n_in,
                              void* d_out, int out_size, void* d_ws, size_t ws_size,
                              hipStream_t stream) {
    const float* u0   = (const float*)d_in[0];
    const float* v0   = (const float*)d_in[1];
    const float* t0   = (const float*)d_in[2];
    const float* s0   = (const float*)d_in[3];
    const float* hz   = (const float*)d_in[4];
    const float* akv  = (const float*)d_in[5];
    const float* akt  = (const float*)d_in[6];
    const float* tfo  = (const float*)d_in[7];
    const float* sfo  = (const float*)d_in[8];
    const float* uss  = (const float*)d_in[9];
    const float* vss  = (const float*)d_in[10];
    const float* usb  = (const float*)d_in[11];
    const float* vsb  = (const float*)d_in[12];
    const float* fcor = (const float*)d_in[13];

    scm_kernel<<<dim3((NCOLS * 4) / 256), dim3(256), 0, stream>>>(
        u0, v0, t0, s0, hz, akv, akt, tfo, sfo, uss, vss, usb, vsb, fcor,
        (float*)d_out);
}

// Round 3
// 609.277 us; speedup vs baseline: 1.0039x; 1.0039x over previous
//
#include <hip/hip_runtime.h>
#include <hip/hip_bf16.h>

#define NCOLS 32768
#define NZ 64
#define NT 40
#define DTF 30.0f
#define GAMMAC 0.55f

typedef _Float16 f16;

// swap lanes (0,1) and (2,3) within each quad: u<->v, t<->s
__device__ __forceinline__ float dpp_swap1(float x) {
    return __int_as_float(__builtin_amdgcn_mov_dpp(__float_as_int(x), 0xB1, 0xF, 0xF, true));
}
__device__ __forceinline__ unsigned int packh2(float a, float b) {
    union { f16 h[2]; unsigned int u; } v;
    v.h[0] = (f16)a; v.h[1] = (f16)b;
    return v.u;
}
__device__ __forceinline__ float lo16f(unsigned int x) {
    union { unsigned int u; f16 h[2]; } v; v.u = x;
    return (float)v.h[0];
}
__device__ __forceinline__ float hi16f(unsigned int x) {
    union { unsigned int u; f16 h[2]; } v; v.u = x;
    return (float)v.h[1];
}

// waves_per_eu pinned to (2,2): the per-thread state (tau[64] + 128 packed
// coefficient regs) needs ~210 VGPRs. With only a *minimum* occupancy bound,
// LLVM's perf-hint heuristic targeted 4 waves/EU (128 VGPRs) and spilled the
// arrays to scratch (rocprof: 406MB FETCH / 194MB WRITE vs 73/32 ideal).
// Pinning max=2 gives the allocator the full 256-VGPR budget -> no spills.
__global__ __launch_bounds__(256)
__attribute__((amdgpu_waves_per_eu(2, 2)))
void scm_kernel(
    const float* __restrict__ u0, const float* __restrict__ v0,
    const float* __restrict__ t0, const float* __restrict__ s0,
    const float* __restrict__ hz, const float* __restrict__ akv,
    const float* __restrict__ akt, const float* __restrict__ tfo,
    const float* __restrict__ sfo, const float* __restrict__ uss,
    const float* __restrict__ vss, const float* __restrict__ usb,
    const float* __restrict__ vsb, const float* __restrict__ fcor,
    float* __restrict__ out)
{
    const int tid = blockIdx.x * 256 + threadIdx.x;
    const int field = tid & 3;          // 0=u 1=v 2=t 3=s
    const int col = tid >> 2;

    const float* ak  = (field < 2) ? akv : akt;
    const float* st0 = (field == 0) ? u0 : (field == 1) ? v0 : (field == 2) ? t0 : s0;

    // per-column Coriolis scalars (u,v only)
    float alpha = 1.0f, beta = 0.0f;
    {
        float fc   = fcor[col];
        float dtfc = DTF * fc;
        float cff  = dtfc * dtfc;
        float cff1 = 1.0f / (1.0f + GAMMAC * GAMMAC * cff);
        float coefc = 1.0f - GAMMAC * (1.0f - GAMMAC) * cff;
        if (field == 0)      { alpha = cff1 * coefc; beta =  cff1 * dtfc; }
        else if (field == 1) { alpha = cff1 * coefc; beta = -cff1 * dtfc; }
    }

    float bnd0 = 0.f, bnd63 = 0.f;
    if (field == 0)      { bnd0 = -DTF * usb[col]; bnd63 = DTF * uss[col]; }
    else if (field == 1) { bnd0 = -DTF * vsb[col]; bnd63 = DTF * vss[col]; }

    // ---- load hz ----
    float hzv[NZ];
    {
        const float4* hp = (const float4*)(hz + (size_t)col * NZ);
        #pragma unroll
        for (int k4 = 0; k4 < NZ / 4; ++k4) {
            float4 h = hp[k4];
            hzv[4*k4+0] = h.x; hzv[4*k4+1] = h.y;
            hzv[4*k4+2] = h.z; hzv[4*k4+3] = h.w;
        }
    }

    const float* akc = ak + (size_t)col * (NZ + 1);
    const float* fr  = ((field == 2) ? tfo : sfo) + (size_t)col * NZ;

    // ---- precompute folded Thomas coefficients, fp16-packed ----
    // a[k] = -2dt*ak[k]/(hz[k-1]+hz[k]) (a[0]=0); c[k] = a[k+1] (c[63]=0)
    // b[k] = hz[k]-a[k]-c[k]; g=1/(b-a*cp_prev); cp=c*g
    // fwd: dp[k] = hg[k]*(alpha*own+beta*oth) + fg[k] - e[k]*dp[k-1]
    unsigned int hgfg[NZ], ecp[NZ];
    {
        float cpprev = 0.f;
        float aik = 0.f;               // a[0] = 0
        #pragma unroll
        for (int k = 0; k < NZ; ++k) {
            float aik1 = 0.f;
            if (k < NZ - 1)
                aik1 = (-2.0f * DTF) * akc[k + 1] / (hzv[k] + hzv[k + 1]);
            float bk    = hzv[k] - aik - aik1;
            float denom = bk - aik * cpprev;
            float g     = 1.0f / denom;
            float cpk   = aik1 * g;
            float fgk;
            if (field >= 2) fgk = (DTF * fr[k]) * g;
            else            fgk = (k == 0 ? bnd0 : (k == NZ - 1 ? bnd63 : 0.0f)) * g;
            hgfg[k] = packh2(hzv[k] * g, fgk);
            ecp[k]  = packh2(-aik * g, -cpk);
            cpprev = cpk;
            aik = aik1;
        }
    }

    // ---- load state (hzv dead from here; reuse of its registers expected) ----
    float tau[NZ];
    {
        const float4* sp = (const float4*)(st0 + (size_t)col * NZ);
        #pragma unroll
        for (int k4 = 0; k4 < NZ / 4; ++k4) {
            float4 s = sp[k4];
            tau[4*k4+0] = s.x; tau[4*k4+1] = s.y;
            tau[4*k4+2] = s.z; tau[4*k4+3] = s.w;
        }
    }

    // deviation shift for t,s: the solve conserves constants exactly
    // (row sums of M equal hz), so evolve tau = state - mean and re-add at
    // the end. Keeps state O(1) so fp16 coefficient rounding cannot excite
    // the conserved mode (which would accumulate linearly over 40 steps).
    float meanadd = 0.0f;
    if (field >= 2) {
        float ssum = 0.f;
        #pragma unroll
        for (int k = 0; k < NZ; ++k) ssum += tau[k];
        meanadd = ssum * (1.0f / NZ);
        #pragma unroll
        for (int k = 0; k < NZ; ++k) tau[k] -= meanadd;
    }

    // ---- 40 time steps, fully in registers ----
    for (int n = 0; n < NT; ++n) {
        float dpprev = 0.f;
        #pragma unroll
        for (int k = 0; k < NZ; ++k) {
            float own = tau[k];
            float oth = dpp_swap1(own);                // partner field's value
            float m   = fmaf(beta, oth, alpha * own);  // t,s: beta=0,alpha=1
            unsigned int hf = hgfg[k];
            float dp  = fmaf(lo16f(hf), m, hi16f(hf)); // hg*m + fg
            dp = fmaf(lo16f(ecp[k]), dpprev, dp);      // - e*dp_prev
            tau[k] = dp;
            dpprev = dp;
        }
        float xn = 0.f;
        #pragma unroll
        for (int k = NZ - 1; k >= 0; --k) {
            float x = fmaf(hi16f(ecp[k]), xn, tau[k]); // dp - cp*x_next
            tau[k] = x;
            xn = x;
        }
    }

    // ---- store f32 output: out[field][col][k] ----
    float* op = out + ((size_t)field * NCOLS + col) * NZ;
    #pragma unroll
    for (int k4 = 0; k4 < NZ / 4; ++k4) {
        float4 w;
        w.x = tau[4*k4+0] + meanadd;
        w.y = tau[4*k4+1] + meanadd;
        w.z = tau[4*k4+2] + meanadd;
        w.w = tau[4*k4+3] + meanadd;
        ((float4*)op)[k4] = w;
    }
}

extern "C" void kernel_launch(void* const* d_in, const int* in_sizes, int n_in,
                              void* d_out, int out_size, void* d_ws, size_t ws_size,
                              hipStream_t stream) {
    const float* u0   = (const float*)d_in[0];
    const float* v0   = (const float*)d_in[1];
    const float* t0   = (const float*)d_in[2];
    const float* s0   = (const float*)d_in[3];
    const float* hz   = (const float*)d_in[4];
    const float* akv  = (const float*)d_in[5];
    const float* akt  = (const float*)d_in[6];
    const float* tfo  = (const float*)d_in[7];
    const float* sfo  = (const float*)d_in[8];
    const float* uss  = (const float*)d_in[9];
    const float* vss  = (const float*)d_in[10];
    const float* usb  = (const float*)d_in[11];
    const float* vsb  = (const float*)d_in[12];
    const float* fcor = (const float*)d_in[13];

    scm_kernel<<<dim3((NCOLS * 4) / 256), dim3(256), 0, stream>>>(
        u0, v0, t0, s0, hz, akv, akt, tfo, sfo, uss, vss, usb, vsb, fcor,
        (float*)d_out);
}

// Round 4
// 490.747 us; speedup vs baseline: 1.2464x; 1.2415x over previous
//
#include <hip/hip_runtime.h>
#include <hip/hip_bf16.h>

#define NCOLS 32768
#define NZ 64
#define NT 40
#define DTF 30.0f
#define GAMMAC 0.55f

typedef _Float16 f16;

// swap lanes (0,1) and (2,3) within each quad: u<->v, t<->s
__device__ __forceinline__ float dpp_swap1(float x) {
    return __int_as_float(__builtin_amdgcn_mov_dpp(__float_as_int(x), 0xB1, 0xF, 0xF, true));
}
__device__ __forceinline__ unsigned int packh2(float a, float b) {
    union { f16 h[2]; unsigned int u; } v;
    v.h[0] = (f16)a; v.h[1] = (f16)b; return v.u;
}
__device__ __forceinline__ unsigned short f16bits(float a) {
    union { f16 h; unsigned short u; } v; v.h = (f16)a; return v.u;
}
__device__ __forceinline__ float lo16f(unsigned int x) {
    union { unsigned int u; f16 h[2]; } v; v.u = x; return (float)v.h[0];
}
__device__ __forceinline__ float hi16f(unsigned int x) {
    union { unsigned int u; f16 h[2]; } v; v.u = x; return (float)v.h[1];
}
__device__ __forceinline__ float h16f(unsigned short x) {
    union { unsigned short u; f16 h; } v; v.u = x; return (float)v.h;
}

// Coefficients live in LDS (explicitly managed), NOT registers: r2/r3 showed
// the allocator caps this kernel at 128 VGPRs and spills loop-resident arrays
// to scratch (455MB FETCH vs 73MB ideal). Register demand here is tau[64]+
// ~20 temps < 128 -> structurally no spills.
// Sharing: u,v share akv-derived (hg,e,cp); t,s share akt-derived ones ->
// stored per PAIR (p = ltid>>1). Only fg is per-thread.
// LDS: W 32KB + CP 16KB + FG 32KB = 80KB/block -> 2 blocks/CU, 2 waves/SIMD.
__global__ __launch_bounds__(256, 2) void scm_kernel(
    const float* __restrict__ u0, const float* __restrict__ v0,
    const float* __restrict__ t0, const float* __restrict__ s0,
    const float* __restrict__ hz, const float* __restrict__ akv,
    const float* __restrict__ akt, const float* __restrict__ tfo,
    const float* __restrict__ sfo, const float* __restrict__ uss,
    const float* __restrict__ vss, const float* __restrict__ usb,
    const float* __restrict__ vsb, const float* __restrict__ fcor,
    float* __restrict__ out)
{
    __shared__ unsigned int   Wsh[NZ * 128];   // (hg lo, e hi) f16x2, [k][pair]
    __shared__ unsigned short CPsh[NZ * 128];  // -cp f16, [k][pair]
    __shared__ unsigned short FGsh[NZ * 256];  // fg f16, [k][thread]

    const int ltid  = threadIdx.x;
    const int tid   = blockIdx.x * 256 + ltid;
    const int field = tid & 3;          // 0=u 1=v 2=t 3=s
    const int col   = tid >> 2;
    const int p     = ltid >> 1;        // pair index: (col_in_block, akv/akt)

    const float* ak  = (field < 2) ? akv : akt;
    const float* st0 = (field == 0) ? u0 : (field == 1) ? v0 : (field == 2) ? t0 : s0;

    // per-column Coriolis scalars (u,v only)
    float alpha = 1.0f, beta = 0.0f;
    {
        float fc   = fcor[col];
        float dtfc = DTF * fc;
        float cff  = dtfc * dtfc;
        float cff1 = 1.0f / (1.0f + GAMMAC * GAMMAC * cff);
        float coefc = 1.0f - GAMMAC * (1.0f - GAMMAC) * cff;
        if (field == 0)      { alpha = cff1 * coefc; beta =  cff1 * dtfc; }
        else if (field == 1) { alpha = cff1 * coefc; beta = -cff1 * dtfc; }
    }

    float bnd0 = 0.f, bnd63 = 0.f;
    if (field == 0)      { bnd0 = -DTF * usb[col]; bnd63 = DTF * uss[col]; }
    else if (field == 1) { bnd0 = -DTF * vsb[col]; bnd63 = DTF * vss[col]; }

    // ---- load hz (build phase only; dead before tau is loaded) ----
    float hzv[NZ];
    {
        const float4* hp = (const float4*)(hz + (size_t)col * NZ);
        #pragma unroll
        for (int k4 = 0; k4 < NZ / 4; ++k4) {
            float4 h = hp[k4];
            hzv[4*k4+0] = h.x; hzv[4*k4+1] = h.y;
            hzv[4*k4+2] = h.z; hzv[4*k4+3] = h.w;
        }
    }

    const float* akc = ak + (size_t)col * (NZ + 1);
    const float* fr  = ((field == 2) ? tfo : sfo) + (size_t)col * NZ;

    // ---- build folded Thomas coefficients (all threads run the uniform
    // chain; even thread of each pair publishes the shared part) ----
    {
        float cpprev = 0.f;
        float aik = 0.f;               // a[0] = 0
        #pragma unroll
        for (int k = 0; k < NZ; ++k) {
            float aik1 = 0.f;
            if (k < NZ - 1)
                aik1 = (-2.0f * DTF) * akc[k + 1] / (hzv[k] + hzv[k + 1]);
            float bk    = hzv[k] - aik - aik1;
            float denom = bk - aik * cpprev;
            float g     = 1.0f / denom;
            float cpk   = aik1 * g;
            float fgk;
            if (field >= 2) fgk = (DTF * fr[k]) * g;
            else            fgk = (k == 0 ? bnd0 : (k == NZ - 1 ? bnd63 : 0.0f)) * g;
            if ((ltid & 1) == 0) {
                Wsh[k * 128 + p]  = packh2(hzv[k] * g, -aik * g);
                CPsh[k * 128 + p] = f16bits(-cpk);
            }
            FGsh[k * 256 + ltid] = f16bits(fgk);
            cpprev = cpk;
            aik = aik1;
        }
    }

    // ---- load state ----
    float tau[NZ];
    {
        const float4* sp = (const float4*)(st0 + (size_t)col * NZ);
        #pragma unroll
        for (int k4 = 0; k4 < NZ / 4; ++k4) {
            float4 s = sp[k4];
            tau[4*k4+0] = s.x; tau[4*k4+1] = s.y;
            tau[4*k4+2] = s.z; tau[4*k4+3] = s.w;
        }
    }

    // deviation shift for t,s: the solve conserves constants exactly, so
    // evolve tau = state - mean; re-add at the end. Keeps state O(1) so f16
    // coefficient rounding can't excite the conserved mode.
    float meanadd = 0.0f;
    if (field >= 2) {
        float ssum = 0.f;
        #pragma unroll
        for (int k = 0; k < NZ; ++k) ssum += tau[k];
        meanadd = ssum * (1.0f / NZ);
        #pragma unroll
        for (int k = 0; k < NZ; ++k) tau[k] -= meanadd;
    }

    __syncthreads();   // coefficients published; read-only from here on

    // ---- 40 time steps: tau in registers, coefficients from LDS ----
    for (int n = 0; n < NT; ++n) {
        float dpprev = 0.f;
        #pragma unroll
        for (int k = 0; k < NZ; ++k) {
            float own = tau[k];
            float oth = dpp_swap1(own);                 // partner field
            float m   = fmaf(beta, oth, alpha * own);   // t,s: beta=0,alpha=1
            unsigned int w = Wsh[k * 128 + p];          // (hg, e)
            float fgv = h16f(FGsh[k * 256 + ltid]);
            float dp  = fmaf(lo16f(w), m, fgv);         // hg*m + fg
            dp = fmaf(hi16f(w), dpprev, dp);            // - e*dp_prev
            tau[k] = dp;
            dpprev = dp;
        }
        float xn = 0.f;
        #pragma unroll
        for (int k = NZ - 1; k >= 0; --k) {
            float x = fmaf(h16f(CPsh[k * 128 + p]), xn, tau[k]); // dp - cp*x_next
            tau[k] = x;
            xn = x;
        }
    }

    // ---- store f32 output: out[field][col][k] ----
    float* op = out + ((size_t)field * NCOLS + col) * NZ;
    #pragma unroll
    for (int k4 = 0; k4 < NZ / 4; ++k4) {
        float4 w;
        w.x = tau[4*k4+0] + meanadd;
        w.y = tau[4*k4+1] + meanadd;
        w.z = tau[4*k4+2] + meanadd;
        w.w = tau[4*k4+3] + meanadd;
        ((float4*)op)[k4] = w;
    }
}

extern "C" void kernel_launch(void* const* d_in, const int* in_sizes, int n_in,
                              void* d_out, int out_size, void* d_ws, size_t ws_size,
                              hipStream_t stream) {
    const float* u0   = (const float*)d_in[0];
    const float* v0   = (const float*)d_in[1];
    const float* t0   = (const float*)d_in[2];
    const float* s0   = (const float*)d_in[3];
    const float* hz   = (const float*)d_in[4];
    const float* akv  = (const float*)d_in[5];
    const float* akt  = (const float*)d_in[6];
    const float* tfo  = (const float*)d_in[7];
    const float* sfo  = (const float*)d_in[8];
    const float* uss  = (const float*)d_in[9];
    const float* vss  = (const float*)d_in[10];
    const float* usb  = (const float*)d_in[11];
    const float* vsb  = (const float*)d_in[12];
    const float* fcor = (const float*)d_in[13];

    scm_kernel<<<dim3((NCOLS * 4) / 256), dim3(256), 0, stream>>>(
        u0, v0, t0, s0, hz, akv, akt, tfo, sfo, uss, vss, usb, vsb, fcor,
        (float*)d_out);
}

// Round 5
// 147.926 us; speedup vs baseline: 4.1350x; 3.3175x over previous
//
#include <hip/hip_runtime.h>
#include <hip/hip_bf16.h>

#define NCOLS 32768
#define NZ 64
#define NT 40
#define DTF 30.0f
#define GAMMAC 0.55f

typedef _Float16 f16;

// Cap the pre-RA scheduler's prefetch window: without these fences it hoists
// dozens of independent ds_read results above their uses, inflating live
// ranges past the 128-VGPR budget and spilling to scratch (r4: 195MB excess
// FETCH at 650GB/s = the whole runtime).
#define SBAR() __builtin_amdgcn_sched_barrier(0)

// swap lanes (0,1) and (2,3) within each quad: u<->v, t<->s
__device__ __forceinline__ float dpp_swap1(float x) {
    return __int_as_float(__builtin_amdgcn_mov_dpp(__float_as_int(x), 0xB1, 0xF, 0xF, true));
}
__device__ __forceinline__ unsigned int packh2(float a, float b) {
    union { f16 h[2]; unsigned int u; } v;
    v.h[0] = (f16)a; v.h[1] = (f16)b; return v.u;
}
__device__ __forceinline__ unsigned short f16bits(float a) {
    union { f16 h; unsigned short u; } v; v.h = (f16)a; return v.u;
}
__device__ __forceinline__ float lo16f(unsigned int x) {
    union { unsigned int u; f16 h[2]; } v; v.u = x; return (float)v.h[0];
}
__device__ __forceinline__ float hi16f(unsigned int x) {
    union { unsigned int u; f16 h[2]; } v; v.u = x; return (float)v.h[1];
}
__device__ __forceinline__ float h16f(unsigned short x) {
    union { unsigned short u; f16 h; } v; v.u = x; return (float)v.h;
}

// Coefficients in LDS, shared per pair (u,v <- akv; t,s <- akt); only fg is
// per-thread. LDS: W 32KB + CP 16KB + FG 32KB = 80KB -> 2 blocks/CU.
// Per-thread registers: tau[64] + ~15 temps; sched_barriers bound prefetch.
__global__ __launch_bounds__(256, 2) void scm_kernel(
    const float* __restrict__ u0, const float* __restrict__ v0,
    const float* __restrict__ t0, const float* __restrict__ s0,
    const float* __restrict__ hz, const float* __restrict__ akv,
    const float* __restrict__ akt, const float* __restrict__ tfo,
    const float* __restrict__ sfo, const float* __restrict__ uss,
    const float* __restrict__ vss, const float* __restrict__ usb,
    const float* __restrict__ vsb, const float* __restrict__ fcor,
    float* __restrict__ out)
{
    __shared__ unsigned int   Wsh[NZ * 128];   // (hg lo, e hi) f16x2, [k][pair]
    __shared__ unsigned short CPsh[NZ * 128];  // -cp f16, [k][pair]
    __shared__ unsigned short FGsh[NZ * 256];  // fg f16, [k][thread]

    const int ltid  = threadIdx.x;
    const int tid   = blockIdx.x * 256 + ltid;
    const int field = tid & 3;          // 0=u 1=v 2=t 3=s
    const int col   = tid >> 2;
    const int p     = ltid >> 1;        // pair index

    const float* ak  = (field < 2) ? akv : akt;
    const float* st0 = (field == 0) ? u0 : (field == 1) ? v0 : (field == 2) ? t0 : s0;

    // per-column Coriolis scalars (u,v only)
    float alpha = 1.0f, beta = 0.0f;
    {
        float fc   = fcor[col];
        float dtfc = DTF * fc;
        float cff  = dtfc * dtfc;
        float cff1 = 1.0f / (1.0f + GAMMAC * GAMMAC * cff);
        float coefc = 1.0f - GAMMAC * (1.0f - GAMMAC) * cff;
        if (field == 0)      { alpha = cff1 * coefc; beta =  cff1 * dtfc; }
        else if (field == 1) { alpha = cff1 * coefc; beta = -cff1 * dtfc; }
    }

    float bnd0 = 0.f, bnd63 = 0.f;
    if (field == 0)      { bnd0 = -DTF * usb[col]; bnd63 = DTF * uss[col]; }
    else if (field == 1) { bnd0 = -DTF * vsb[col]; bnd63 = DTF * vss[col]; }

    const float* hzc = hz + (size_t)col * NZ;
    const float* akc = ak + (size_t)col * (NZ + 1);
    const float* fr  = ((field == 2) ? tfo : sfo) + (size_t)col * NZ;

    // ---- build folded Thomas coefficients, STREAMED (no hz array) ----
    // a[k] = -2dt*ak[k]/(hz[k-1]+hz[k]); c[k]=a[k+1]; b[k]=hz[k]-a[k]-c[k]
    // g=1/(b-a*cp_prev); publish hg=hz*g, e=a*g, cp=c*g, fg=rhs*g (f16)
    {
        float cpprev = 0.f;
        float aik = 0.f;               // a[0] = 0
        float hk = hzc[0];
        #pragma unroll
        for (int k = 0; k < NZ; ++k) {
            float hk1 = 0.f, aik1 = 0.f;
            if (k < NZ - 1) {
                hk1  = hzc[k + 1];
                aik1 = (-2.0f * DTF) * akc[k + 1] / (hk + hk1);
            }
            float bk    = hk - aik - aik1;
            float denom = bk - aik * cpprev;
            float g     = 1.0f / denom;
            float cpk   = aik1 * g;
            float fgk;
            if (field >= 2) fgk = (DTF * fr[k]) * g;
            else            fgk = (k == 0 ? bnd0 : (k == NZ - 1 ? bnd63 : 0.0f)) * g;
            if ((ltid & 1) == 0) {
                Wsh[k * 128 + p]  = packh2(hk * g, -aik * g);
                CPsh[k * 128 + p] = f16bits(-cpk);
            }
            FGsh[k * 256 + ltid] = f16bits(fgk);
            cpprev = cpk;
            aik = aik1;
            hk  = hk1;
            if ((k & 15) == 15) SBAR();
        }
    }

    // ---- load state ----
    float tau[NZ];
    {
        const float4* sp = (const float4*)(st0 + (size_t)col * NZ);
        #pragma unroll
        for (int k4 = 0; k4 < NZ / 4; ++k4) {
            float4 s = sp[k4];
            tau[4*k4+0] = s.x; tau[4*k4+1] = s.y;
            tau[4*k4+2] = s.z; tau[4*k4+3] = s.w;
        }
    }

    // deviation shift for t,s: the solve conserves constants exactly, so
    // evolve tau = state - mean; re-add at the end. Keeps state O(1) so f16
    // coefficient rounding can't excite the conserved mode.
    float meanadd = 0.0f;
    if (field >= 2) {
        float ssum = 0.f;
        #pragma unroll
        for (int k = 0; k < NZ; ++k) ssum += tau[k];
        meanadd = ssum * (1.0f / NZ);
        #pragma unroll
        for (int k = 0; k < NZ; ++k) tau[k] -= meanadd;
    }

    __syncthreads();   // coefficients published; read-only from here on

    // ---- 40 time steps: tau in registers, coefficients from LDS ----
    for (int n = 0; n < NT; ++n) {
        float dpprev = 0.f;
        #pragma unroll
        for (int k = 0; k < NZ; ++k) {
            float own = tau[k];
            float oth = dpp_swap1(own);                 // partner field
            float m   = fmaf(beta, oth, alpha * own);   // t,s: beta=0,alpha=1
            unsigned int w = Wsh[k * 128 + p];          // (hg, e)
            float fgv = h16f(FGsh[k * 256 + ltid]);
            float dp  = fmaf(lo16f(w), m, fgv);         // hg*m + fg
            dp = fmaf(hi16f(w), dpprev, dp);            // - e*dp_prev
            tau[k] = dp;
            dpprev = dp;
            if ((k & 15) == 15) SBAR();
        }
        float xn = 0.f;
        #pragma unroll
        for (int k = NZ - 1; k >= 0; --k) {
            float x = fmaf(h16f(CPsh[k * 128 + p]), xn, tau[k]); // dp - cp*xn
            tau[k] = x;
            xn = x;
            if ((k & 15) == 0) SBAR();
        }
    }

    // ---- store f32 output: out[field][col][k] ----
    float* op = out + ((size_t)field * NCOLS + col) * NZ;
    #pragma unroll
    for (int k4 = 0; k4 < NZ / 4; ++k4) {
        float4 w;
        w.x = tau[4*k4+0] + meanadd;
        w.y = tau[4*k4+1] + meanadd;
        w.z = tau[4*k4+2] + meanadd;
        w.w = tau[4*k4+3] + meanadd;
        ((float4*)op)[k4] = w;
    }
}

extern "C" void kernel_launch(void* const* d_in, const int* in_sizes, int n_in,
                              void* d_out, int out_size, void* d_ws, size_t ws_size,
                              hipStream_t stream) {
    const float* u0   = (const float*)d_in[0];
    const float* v0   = (const float*)d_in[1];
    const float* t0   = (const float*)d_in[2];
    const float* s0   = (const float*)d_in[3];
    const float* hz   = (const float*)d_in[4];
    const float* akv  = (const float*)d_in[5];
    const float* akt  = (const float*)d_in[6];
    const float* tfo  = (const float*)d_in[7];
    const float* sfo  = (const float*)d_in[8];
    const float* uss  = (const float*)d_in[9];
    const float* vss  = (const float*)d_in[10];
    const float* usb  = (const float*)d_in[11];
    const float* vsb  = (const float*)d_in[12];
    const float* fcor = (const float*)d_in[13];

    scm_kernel<<<dim3((NCOLS * 4) / 256), dim3(256), 0, stream>>>(
        u0, v0, t0, s0, hz, akv, akt, tfo, sfo, uss, vss, usb, vsb, fcor,
        (float*)d_out);
}